// Round 1
// baseline (111.924 us; speedup 1.0000x reference)
//
#include <hip/hip_runtime.h>

// CapsNet routing: N=32, C=32, D=16 (=P*P), W=H=16 (S=256), K=10, n_rout=3.
// Factorized: b = lr . U (U = wt . vec), M = c^T . lr, s = M . wt.
// Only l (16 MB) is re-read per iteration; U/M are 655 KB each in d_ws.

#define KK 10
#define PP 16
#define CC 32
#define SS 256
#define NN 32

// U[n][c][k][ij] = sum_dd w[c][k][j][dd] * vec[n][k][i*4+dd]
__global__ __launch_bounds__(256) void u_from_vec_kernel(
    const float* __restrict__ vec,   // [N][K][16]
    const float* __restrict__ w,     // [C][K][4][4]
    float* __restrict__ U)           // [N][C][K][16]
{
  const int n = blockIdx.x;
  const int t = threadIdx.x;
  __shared__ float v_lds[KK * PP];
  if (t < KK * PP) v_lds[t] = vec[n * KK * PP + t];
  __syncthreads();
  for (int e = t; e < CC * KK * PP; e += 256) {
    const int c  = e / (KK * PP);
    const int r  = e - c * (KK * PP);
    const int k  = r >> 4;
    const int ij = r & 15;
    const int i = ij >> 2, j = ij & 3;
    const float* wp = w + ((c * KK + k) * 4 + j) * 4;
    const float* vp = v_lds + k * PP + i * 4;
    U[n * CC * KK * PP + e] = wp[0]*vp[0] + wp[1]*vp[1] + wp[2]*vp[2] + wp[3]*vp[3];
  }
}

// Per (n,c): compute b_k = lr . U, softmax over k, M[k][ij] = sum_s c_k * lr[ij]
__global__ __launch_bounds__(256) void pass_kernel(
    const float* __restrict__ l,   // [N][C][16][256]
    const float* __restrict__ U,   // [N][C][K][16]
    float* __restrict__ M)         // [N][C][K][16]
{
  const int c = blockIdx.x;
  const int n = blockIdx.y;
  const int s = threadIdx.x;  // 256 spatial positions

  __shared__ float U_lds[KK * PP];
  __shared__ float ct[KK][SS];          // c weights, transposed [k][s]
  __shared__ float lr_lds[PP][SS + 4];  // [ij][s], +4 pad for b128 bank spread

  if (s < KK * PP) U_lds[s] = U[(n * CC + c) * KK * PP + s];

  float lr[PP];
  const float* lb = l + ((size_t)(n * CC + c)) * 4096 + s;
  #pragma unroll
  for (int d = 0; d < PP; ++d) {
    lr[d] = lb[d * SS];       // coalesced: consecutive s -> consecutive addr
    lr_lds[d][s] = lr[d];
  }
  __syncthreads();

  float b[KK];
  float bmax = -1e30f;
  #pragma unroll
  for (int k = 0; k < KK; ++k) {
    float acc = 0.f;
    #pragma unroll
    for (int d = 0; d < PP; ++d) acc += lr[d] * U_lds[k * PP + d];
    b[k] = acc;
    bmax = fmaxf(bmax, acc);
  }
  float ssum = 0.f;
  #pragma unroll
  for (int k = 0; k < KK; ++k) { b[k] = __expf(b[k] - bmax); ssum += b[k]; }
  const float inv = 1.f / ssum;
  #pragma unroll
  for (int k = 0; k < KK; ++k) ct[k][s] = b[k] * inv;
  __syncthreads();

  // Reduce over s: 160 threads, one (k,ij) each; float4 LDS reads.
  if (s < KK * PP) {
    const int k = s >> 4, ij = s & 15;
    float acc = 0.f;
    #pragma unroll 4
    for (int s4 = 0; s4 < SS; s4 += 4) {
      const float4 cv = *(const float4*)&ct[k][s4];          // broadcast (same addr)
      const float4 lv = *(const float4*)&lr_lds[ij][s4];
      acc += cv.x * lv.x + cv.y * lv.y + cv.z * lv.z + cv.w * lv.w;
    }
    M[((n * CC + c) * KK + k) * PP + ij] = acc;
  }
}

// Per n: s[k][m] = sum_{c,j} M * wt ; squash -> gc ; U_next = wt . gc (or outputs)
__global__ __launch_bounds__(256) void update_kernel(
    const float* __restrict__ M,   // [N][C][K][16]
    const float* __restrict__ w,
    float* __restrict__ U,         // written when !last
    float* __restrict__ out_a,     // [N][K]      written when last
    float* __restrict__ out_gc,    // [N][K][16]  written when last
    const int last)
{
  const int n = blockIdx.x;
  const int t = threadIdx.x;
  __shared__ float s_lds[KK * PP];
  __shared__ float f_lds[KK];
  __shared__ float gc_lds[KK * PP];

  if (t < KK * PP) {
    const int k  = t >> 4;
    const int i  = (t >> 2) & 3;
    const int dd = t & 3;
    float acc = 0.f;
    for (int c = 0; c < CC; ++c) {
      const float* Mp = M + ((n * CC + c) * KK + k) * PP + i * 4;
      const float* wp = w + ((c * KK + k) * 4) * 4 + dd;  // + j*4 steps over j
      #pragma unroll
      for (int j = 0; j < 4; ++j) acc += Mp[j] * wp[j * 4];
    }
    s_lds[t] = acc;
  }
  __syncthreads();
  if (t < KK) {
    float sn = 0.f;
    #pragma unroll
    for (int m = 0; m < PP; ++m) { const float v = s_lds[t * PP + m]; sn += v * v; }
    f_lds[t] = sn / (1.f + sn) * rsqrtf(sn);   // squash factor
    if (last) {
      const float gn = sn / (1.f + sn);        // = sqrt(sum gc^2)
      out_a[n * KK + t] = 1.f / (1.f + __expf(-gn));
    }
  }
  __syncthreads();
  if (t < KK * PP) {
    const float gv = s_lds[t] * f_lds[t >> 4];
    gc_lds[t] = gv;
    if (last) out_gc[n * KK * PP + t] = gv;
  }
  __syncthreads();
  if (!last) {
    for (int e = t; e < CC * KK * PP; e += 256) {
      const int c  = e / (KK * PP);
      const int r  = e - c * (KK * PP);
      const int k  = r >> 4;
      const int ij = r & 15;
      const int i = ij >> 2, j = ij & 3;
      const float* wp = w + ((c * KK + k) * 4 + j) * 4;
      const float* gp = gc_lds + k * PP + i * 4;
      U[n * CC * KK * PP + e] = wp[0]*gp[0] + wp[1]*gp[1] + wp[2]*gp[2] + wp[3]*gp[3];
    }
  }
}

extern "C" void kernel_launch(void* const* d_in, const int* in_sizes, int n_in,
                              void* d_out, int out_size, void* d_ws, size_t ws_size,
                              hipStream_t stream) {
  const float* l = (const float*)d_in[0];
  const float* g = (const float*)d_in[1];
  const float* w = (const float*)d_in[2];
  // d_in[3] = n_rout (==3, hardcoded; must be same work every call anyway)

  float* out    = (float*)d_out;
  float* out_a  = out;              // [N][K]
  float* out_gc = out + NN * KK;    // [N][K][16]

  float* U = (float*)d_ws;                 // [N][C][K][16] = 163840 floats
  float* M = U + NN * CC * KK * PP;        // [N][C][K][16] = 163840 floats

  u_from_vec_kernel<<<NN, 256, 0, stream>>>(g, w, U);
  for (int r = 0; r < 3; ++r) {
    pass_kernel<<<dim3(CC, NN), 256, 0, stream>>>(l, U, M);
    update_kernel<<<NN, 256, 0, stream>>>(M, w, U, out_a, out_gc, r == 2);
  }
}